// Round 15
// baseline (72.199 us; speedup 1.0000x reference)
//
#include <hip/hip_runtime.h>
#include <hip/hip_bf16.h>

// ============================================================================
// Round 15: MEASUREMENT ROUND (r8 pattern). Byte-identical to r14 (43.8us
// anchor, passing) + THREE duplicate k_qkv dispatches into scratch.
// dur15 - 43.8 ~= 3*T_qkv  -> locates the post-layout time distribution.
//   X/Q/K/W/OH: [tile][kc][row&31][16];  V: [bh][ks][s][d][H][8]
// Exact algebra (r1-r8): pos branch rank-1 => w[b,h,j]=softmax_j(-s[b,h,j]);
// renorm no-op. bf16 MFMA 32x32x16; C/D col=lane&31, row=(reg&3)+8*(reg>>2)
// +4*(lane>>5). No-max softmax: Wq pre-scaled to exp2 units (sigma~1.44).
// ============================================================================

constexpr int N_ = 1024, PD_ = 16;

typedef short  s8v  __attribute__((ext_vector_type(8)));
typedef float  f16v __attribute__((ext_vector_type(16)));
typedef unsigned u4v __attribute__((ext_vector_type(4)));

__device__ inline unsigned pkbf(float lo, float hi) {
  unsigned r;
  asm("v_cvt_pk_bf16_f32 %0, %1, %2" : "=v"(r) : "v"(lo), "v"(hi));
  return r;
}
__device__ inline short bf16r(float f) {
  unsigned u = __float_as_uint(f);
  u += 0x7fff + ((u >> 16) & 1);
  return (short)(u >> 16);
}
__device__ inline float bfu(short s) {
  return __uint_as_float(((unsigned)(unsigned short)s) << 16);
}

// ---- K1: W^T->frag-major (64 blk) | pos MLP+softmax + pv zero (32 blk) |
//          x->frag-major bf16 (512 blk)  [r13-frozen] ------------------------
__global__ __launch_bounds__(256) void k_prep(
    const float* __restrict__ Wq, const float* __restrict__ Wk,
    const float* __restrict__ Wv, const float* __restrict__ Wo,
    const float* __restrict__ pos, const float* __restrict__ Wp1,
    const float* __restrict__ bp1, const float* __restrict__ Wp2,
    const float* __restrict__ bp2, const float* __restrict__ Wh,
    const float* __restrict__ x,
    short* __restrict__ Wtf, short* __restrict__ Wof, float* __restrict__ Ww,
    short* __restrict__ xf, float* __restrict__ pv)
{
  int bid = blockIdx.x;
  int tid = threadIdx.x;

  if (bid >= 96) {
    size_t idx = ((size_t)(bid - 96) * 256 + tid) * 8;
    int m = (int)(idx >> 8), k0 = (int)(idx & 255);
    const float4* p = (const float4*)(x + idx);
    float4 f0 = p[0], f1 = p[1];
    u4v o = { pkbf(f0.x, f0.y), pkbf(f0.z, f0.w), pkbf(f1.x, f1.y), pkbf(f1.z, f1.w) };
    size_t dst = ((size_t)((m >> 5) * 16 + (k0 >> 4))) * 512 + (m & 31) * 16 + (k0 & 15);
    *(u4v*)(xf + dst) = o;
    return;
  }

  if (bid < 64) {
    __shared__ float tile[64][65];
    int mat = bid >> 4, t = bid & 15;
    int k0t = (t >> 2) * 64, c0t = (t & 3) * 64;
    const float* W = mat == 0 ? Wq : mat == 1 ? Wk : mat == 2 ? Wv : Wo;
    float scale = (mat == 0) ? 0.2550348662f : 1.0f;   // log2(e)/sqrt(32)
#pragma unroll
    for (int i = 0; i < 16; ++i) {
      int e = tid + i * 256;
      int kr = e >> 6, cc = e & 63;
      tile[kr][cc] = W[(size_t)(k0t + kr) * 256 + c0t + cc];
    }
    __syncthreads();
    short* dst = (mat == 3) ? Wof : (Wtf + mat * 65536);
#pragma unroll
    for (int i = 0; i < 16; ++i) {
      int e = tid + i * 256;
      int cr = e >> 6, kk = e & 63;
      int c = c0t + cr, k = k0t + kk;
      size_t a = ((size_t)((c >> 5) * 16 + (k >> 4))) * 512 + (c & 31) * 16 + (k & 15);
      dst[a] = bf16r(tile[kk][cr] * scale);
    }
    return;
  }

  __shared__ float sWp1[256], sbp1[16], sWp2[512], sbp2[32], sWhc[32];
  __shared__ float redm[4], reds[4];
  int bh = bid - 64;
  int b = bh >> 3, h = bh & 7;
  if (tid < 32) pv[bh * 32 + tid] = 0.0f;
  sWp1[tid] = Wp1[tid];
  sWp2[tid] = Wp2[tid];
  sWp2[tid + 256] = Wp2[tid + 256];
  if (tid < 16) sbp1[tid] = bp1[tid];
  if (tid < 32) { sbp2[tid] = bp2[tid]; sWhc[tid] = Wh[tid * 8 + h]; }
  __syncthreads();

  float a[4];
#pragma unroll
  for (int nn = 0; nn < 4; ++nn) {
    int n = nn * 256 + tid;
    const float* prow = pos + (size_t)((b << 10) + n) * PD_;
    float pr[16];
#pragma unroll
    for (int r = 0; r < 16; ++r) pr[r] = prow[r];
    float h1[16];
#pragma unroll
    for (int c = 0; c < 16; ++c) {
      float v = sbp1[c];
#pragma unroll
      for (int r = 0; r < 16; ++r) v = fmaf(pr[r], sWp1[r * 16 + c], v);
      h1[c] = fmaxf(v, 0.0f);
    }
    float s = 0.0f;
#pragma unroll
    for (int d = 0; d < 32; ++d) {
      float v = sbp2[d];
#pragma unroll
      for (int c = 0; c < 16; ++c) v = fmaf(h1[c], sWp2[c * 32 + d], v);
      s = fmaf(v, sWhc[d], s);
    }
    a[nn] = -s;   // bh[h] constant over n: cancels
  }
  float m = fmaxf(fmaxf(a[0], a[1]), fmaxf(a[2], a[3]));
#pragma unroll
  for (int off = 32; off >= 1; off >>= 1) m = fmaxf(m, __shfl_xor(m, off));
  if ((tid & 63) == 0) redm[tid >> 6] = m;
  __syncthreads();
  float M = fmaxf(fmaxf(redm[0], redm[1]), fmaxf(redm[2], redm[3]));
  float e0 = __expf(a[0] - M), e1 = __expf(a[1] - M);
  float e2 = __expf(a[2] - M), e3 = __expf(a[3] - M);
  float su = e0 + e1 + e2 + e3;
#pragma unroll
  for (int off = 32; off >= 1; off >>= 1) su += __shfl_xor(su, off);
  if ((tid & 63) == 0) reds[tid >> 6] = su;
  __syncthreads();
  float inv = 1.0f / (reds[0] + reds[1] + reds[2] + reds[3]);
  float* wr = Ww + (size_t)bh * N_;
  wr[tid]        = e0 * inv;
  wr[tid + 256]  = e1 * inv;
  wr[tid + 512]  = e2 * inv;
  wr[tid + 768]  = e3 * inv;
}

// ---- K2: QKV GEMM, frag-major operands + pv atomics  [r13-frozen] ----------
__global__ __launch_bounds__(256) void k_qkv(
    const short* __restrict__ xf, const short* __restrict__ Wtf,
    const float* __restrict__ Ww,
    short* __restrict__ Qf, short* __restrict__ Kf, short* __restrict__ Vf,
    float* __restrict__ pv)
{
  int tid = threadIdx.x;
  int w = tid >> 6, l = tid & 63, H = l >> 5, li = l & 31;
  int bid = blockIdx.x;
  int cb = bid % 12, mb = bid / 12;
  int m0 = mb * 64 + (w & 1) * 32;
  int c0 = cb * 64 + (w >> 1) * 32;
  int mat = c0 >> 8, mc = c0 & 255;
  const short* Apf = xf + ((size_t)((m0 >> 5) * 16)) * 512 + li * 16 + 8 * H;
  const short* Bpf = Wtf + (size_t)mat * 65536
                   + ((size_t)((mc >> 5) * 16)) * 512 + li * 16 + 8 * H;
  f16v acc = {};
#pragma unroll
  for (int kc = 0; kc < 16; ++kc) {
    s8v af = *(const s8v*)(Apf + kc * 512);
    s8v bf = *(const s8v*)(Bpf + kc * 512);
    acc = __builtin_amdgcn_mfma_f32_32x32x16_bf16(af, bf, acc, 0, 0, 0);
  }
  int h = mc >> 5;
  int b = m0 >> 10, nb = m0 & 1023;
  int bh = b * 8 + h;
  if (mat < 2) {
    short* Dst = (mat == 0) ? Qf : Kf;
    size_t base = ((size_t)(bh * 2 + (li >> 4))) * 1024;
#pragma unroll
    for (int r = 0; r < 16; ++r) {
      int crow = (r & 3) + 8 * (r >> 2) + 4 * H;
      Dst[(base + nb + crow) * 16 + (li & 15)] = bf16r(acc[r]);
    }
  } else {
    int ks = nb >> 5;
#pragma unroll
    for (int q2 = 0; q2 < 4; ++q2) {
      uint2 val = make_uint2(pkbf(acc[q2 * 4 + 0], acc[q2 * 4 + 1]),
                             pkbf(acc[q2 * 4 + 2], acc[q2 * 4 + 3]));
      size_t addr = (((size_t)(bh * 32 + ks) * 2 + (q2 >> 1)) * 32 + li) * 16
                  + (q2 & 1) * 8 + 4 * H;
      *(uint2*)(Vf + addr) = val;
    }
    const float* wp = Ww + (size_t)bh * N_ + nb;
    float part = 0.0f;
#pragma unroll
    for (int r = 0; r < 16; ++r) {
      int crow = (r & 3) + 8 * (r >> 2) + 4 * H;
      part = fmaf(wp[crow], acc[r], part);
    }
    atomicAdd(&pv[bh * 32 + li], part);
  }
}

// ---- K3: flash attn, 8 waves x 128 keys (r14-frozen) ------------------------
__global__ __launch_bounds__(512) void k_attn(
    const short* __restrict__ Qf, const short* __restrict__ Kf,
    const short* __restrict__ Vf, const float* __restrict__ pv,
    const float* __restrict__ gate,
    short* __restrict__ OHfh, short* __restrict__ OHfl)
{
  __shared__ float sml[8][32];
  __shared__ float sO[8][32][33];
  int tid = threadIdx.x;
  int w = tid >> 6, l = tid & 63, H = l >> 5, li = l & 31;   // w in 0..7
  int bid = blockIdx.x;
  int bh = (bid & 7) * 4 + (bid >> 8);   // 4 bh per XCD -> K/V L2-resident
  int qb = (bid >> 3) & 31;
  int n0 = qb * 32;

  const short* Qpf = Qf + ((size_t)(bh * 2) * 1024 + n0 + li) * 16 + 8 * H;
  s8v qf0 = *(const s8v*)(Qpf);
  s8v qf1 = *(const s8v*)(Qpf + 16384);
  const short* Kbf = Kf + ((size_t)(bh * 2) * 1024 + li) * 16 + 8 * H;
  const short* Vbf = Vf + ((size_t)(bh * 32) * 2 * 32) * 16 + li * 16 + H * 8;

  f16v acc = {};
  float lsum = 0.0f;

#pragma unroll 2
  for (int ch = 0; ch < 4; ++ch) {
    int jb = w * 128 + ch * 32;
    int ks = jb >> 5;
    const short* Kp = Kbf + (size_t)jb * 16;
    s8v kf0 = *(const s8v*)(Kp);
    s8v kf1 = *(const s8v*)(Kp + 16384);
    const short* Vp = Vbf + (size_t)(ks * 2) * 512;
    s8v vf0 = *(const s8v*)(Vp);
    s8v vf1 = *(const s8v*)(Vp + 512);

    f16v S = {};
    S = __builtin_amdgcn_mfma_f32_32x32x16_bf16(kf0, qf0, S, 0, 0, 0);
    S = __builtin_amdgcn_mfma_f32_32x32x16_bf16(kf1, qf1, S, 0, 0, 0);

    float p[16];
#pragma unroll
    for (int r = 0; r < 16; ++r) {
      p[r] = __builtin_amdgcn_exp2f(S[r]);   // no max: sigma(S)~1.44, safe
      lsum += p[r];
    }

    unsigned a0 = pkbf(p[0], p[1]),  a1 = pkbf(p[2], p[3]);
    unsigned b0 = pkbf(p[4], p[5]),  b1 = pkbf(p[6], p[7]);
    unsigned c0 = pkbf(p[8], p[9]),  c1 = pkbf(p[10], p[11]);
    unsigned d0 = pkbf(p[12], p[13]), d1 = pkbf(p[14], p[15]);
    unsigned sa0 = __shfl_xor(a0, 32), sa1 = __shfl_xor(a1, 32);
    unsigned sb0 = __shfl_xor(b0, 32), sb1 = __shfl_xor(b1, 32);
    unsigned sc0 = __shfl_xor(c0, 32), sc1 = __shfl_xor(c1, 32);
    unsigned sd0 = __shfl_xor(d0, 32), sd1 = __shfl_xor(d1, 32);
    u4v t0 = { H ? sb0 : a0, H ? sb1 : a1, H ? b0 : sa0, H ? b1 : sa1 };
    u4v t1 = { H ? sd0 : c0, H ? sd1 : c1, H ? d0 : sc0, H ? d1 : sc1 };

    acc = __builtin_amdgcn_mfma_f32_32x32x16_bf16(vf0, __builtin_bit_cast(s8v, t0), acc, 0, 0, 0);
    acc = __builtin_amdgcn_mfma_f32_32x32x16_bf16(vf1, __builtin_bit_cast(s8v, t1), acc, 0, 0, 0);
  }

  lsum += __shfl_xor(lsum, 32);
  if (H == 0) sml[w][li] = lsum;
#pragma unroll
  for (int r = 0; r < 16; ++r) {
    int d = (r & 3) + 8 * (r >> 2) + 4 * H;
    sO[w][d][li] = acc[r];
  }
  __syncthreads();

  if (tid < 256) {
    int i = tid >> 3, dq = (tid & 7) * 4;
    float L = sml[0][i] + sml[1][i] + sml[2][i] + sml[3][i]
            + sml[4][i] + sml[5][i] + sml[6][i] + sml[7][i];
    int b = bh >> 3, h = bh & 7;
    float gh = 1.0f / (1.0f + __expf(-gate[h]));
    float invL = (1.0f - gh) / L;
    const float4 pvv = *(const float4*)(pv + bh * 32 + dq);
    float o[4];
#pragma unroll
    for (int q = 0; q < 4; ++q) {
      o[q] = (sO[0][dq + q][i] + sO[1][dq + q][i] + sO[2][dq + q][i] + sO[3][dq + q][i]
            + sO[4][dq + q][i] + sO[5][dq + q][i] + sO[6][dq + q][i] + sO[7][dq + q][i]) * invL;
    }
    o[0] += gh * pvv.x; o[1] += gh * pvv.y; o[2] += gh * pvv.z; o[3] += gh * pvv.w;
    float hi[4], lo[4];
#pragma unroll
    for (int q = 0; q < 4; ++q) {
      hi[q] = bfu(bf16r(o[q]));
      lo[q] = o[q] - hi[q];
    }
    int kc = h * 2 + (dq >> 4);
    int rem = dq & 15;                     // {0,4,8,12}
    size_t addr = ((size_t)((b * 32 + qb) * 16 + kc)) * 512 + i * 16 + rem;
    *(uint2*)(OHfh + addr) = make_uint2(pkbf(hi[0], hi[1]), pkbf(hi[2], hi[3]));
    *(uint2*)(OHfl + addr) = make_uint2(pkbf(lo[0], lo[1]), pkbf(lo[2], lo[3]));
  }
}

// ---- K4: out = (OHhi+OHlo) @ Wo + bo, frag-major operands  [r13-frozen] ----
__global__ __launch_bounds__(256) void k_out(
    const short* __restrict__ OHfh, const short* __restrict__ OHfl,
    const short* __restrict__ Wof, const float* __restrict__ bo,
    float* __restrict__ out)
{
  int tid = threadIdx.x;
  int w = tid >> 6, l = tid & 63, H = l >> 5, li = l & 31;
  int bid = blockIdx.x;
  int m0 = (bid >> 2) * 64 + (w & 1) * 32;
  int c0 = (bid & 3) * 64 + (w >> 1) * 32;
  const short* Ahf = OHfh + ((size_t)((m0 >> 5) * 16)) * 512 + li * 16 + 8 * H;
  const short* Alf = OHfl + ((size_t)((m0 >> 5) * 16)) * 512 + li * 16 + 8 * H;
  const short* Bpf = Wof + ((size_t)((c0 >> 5) * 16)) * 512 + li * 16 + 8 * H;
  f16v acc = {};
#pragma unroll
  for (int kc = 0; kc < 16; ++kc) {
    s8v bf = *(const s8v*)(Bpf + kc * 512);
    s8v ah = *(const s8v*)(Ahf + kc * 512);
    s8v al = *(const s8v*)(Alf + kc * 512);
    acc = __builtin_amdgcn_mfma_f32_32x32x16_bf16(ah, bf, acc, 0, 0, 0);
    acc = __builtin_amdgcn_mfma_f32_32x32x16_bf16(al, bf, acc, 0, 0, 0);
  }
  float bias = bo[c0 + li];
#pragma unroll
  for (int r = 0; r < 16; ++r) {
    int crow = (r & 3) + 8 * (r >> 2) + 4 * H;
    out[(size_t)(m0 + crow) * 256 + c0 + li] = acc[r] + bias;
  }
}

// ============================================================================
extern "C" void kernel_launch(void* const* d_in, const int* in_sizes, int n_in,
                              void* d_out, int out_size, void* d_ws, size_t ws_size,
                              hipStream_t stream) {
  const float* x    = (const float*)d_in[0];
  // d_in[1] = deep_semantics: unused by the reference
  const float* pos  = (const float*)d_in[2];
  const float* Wq   = (const float*)d_in[3];
  const float* Wk   = (const float*)d_in[4];
  const float* Wv   = (const float*)d_in[5];
  const float* Wo   = (const float*)d_in[6];
  const float* bo   = (const float*)d_in[7];
  const float* Wp1  = (const float*)d_in[8];
  const float* bp1  = (const float*)d_in[9];
  const float* Wp2  = (const float*)d_in[10];
  const float* bp2  = (const float*)d_in[11];
  const float* Wh   = (const float*)d_in[12];
  // d_in[13] = bh: cancels in softmax over keys
  const float* gate = (const float*)d_in[14];
  float* out = (float*)d_out;

  char* base = (char*)d_ws;
  short* Qf   = (short*)(base);                               // 2MB
  short* Kf   = (short*)(base + (2u << 20));                  // 2MB
  short* Vf   = (short*)(base + (4u << 20));                  // 2MB
  short* OHfh = (short*)(base + (6u << 20));                  // 2MB
  short* OHfl = (short*)(base + (8u << 20));                  // 2MB
  short* xf   = (short*)(base + (10u << 20));                 // 2MB
  short* Wtf  = (short*)(base + (12u << 20));                 // 384KB
  short* Wof  = (short*)(base + (12u << 20) + (384u << 10));  // 128KB
  float* Ww   = (float*)(base + (12u << 20) + (512u << 10));  // 128KB
  float* pv   = (float*)(base + (12u << 20) + (640u << 10));  // 4KB
  // probe scratch (never read)
  short* Qf2  = (short*)(base + (16u << 20));                 // 2MB
  short* Kf2  = (short*)(base + (18u << 20));                 // 2MB
  short* Vf2  = (short*)(base + (20u << 20));                 // 2MB
  float* pv2  = (float*)(base + (22u << 20));                 // 4KB

  k_prep<<<608,  256, 0, stream>>>(Wq, Wk, Wv, Wo, pos, Wp1, bp1, Wp2, bp2, Wh,
                                   x, Wtf, Wof, Ww, xf, pv);
  k_qkv <<<768,  256, 0, stream>>>(xf, Wtf, Ww, Qf, Kf, Vf, pv);
  // --- amplification probe: 3 duplicate qkv dispatches into scratch ---
  k_qkv <<<768,  256, 0, stream>>>(xf, Wtf, Ww, Qf2, Kf2, Vf2, pv2);
  k_qkv <<<768,  256, 0, stream>>>(xf, Wtf, Ww, Qf2, Kf2, Vf2, pv2);
  k_qkv <<<768,  256, 0, stream>>>(xf, Wtf, Ww, Qf2, Kf2, Vf2, pv2);
  k_attn<<<1024, 512, 0, stream>>>(Qf, Kf, Vf, pv, gate, OHfh, OHfl);
  k_out <<<256,  256, 0, stream>>>(OHfh, OHfl, Wof, bo, out);
}

// Round 16
// 41.077 us; speedup vs baseline: 1.7577x; 1.7577x over previous
//
#include <hip/hip_runtime.h>
#include <hip/hip_bf16.h>

// ============================================================================
// Round 16: XCD-ALIGNED PRODUCER->CONSUMER. All compute bodies byte-frozen
// from r13/r14 (43.8us). Only block-index remaps + per-XCD weight replication:
//   - qkv block writing bh=8b+h runs on XCD 2b+(h>>2)  == attn's reader XCD
//   - prep x-blocks remapped so xf rows are local to their qkv readers
//   - Wtf/Wof replicated 8x (one copy per XCD); readers use copy bid&7
//   - k_out blocks pinned to the XCDs that produced their OH rows
// Assumption: workgroup->XCD is round-robin on blockIdx%8 (guide T1/m09).
// Wrong assumption => still correct, just no speedup (pure remap).
//   X/Q/K/W/OH: [tile][kc][row&31][16];  V: [bh][ks][s][d][H][8]
// Exact algebra (r1-r8): pos branch rank-1 => w[b,h,j]=softmax_j(-s[b,h,j]);
// renorm no-op. bf16 MFMA 32x32x16; C/D col=lane&31, row=(reg&3)+8*(reg>>2)
// +4*(lane>>5). No-max softmax: Wq pre-scaled to exp2 units (sigma~1.44).
// ============================================================================

constexpr int N_ = 1024, PD_ = 16;
constexpr int WTF_CP = 196608;   // 3*65536 shorts per XCD copy
constexpr int WOF_CP = 65536;    // shorts per XCD copy

typedef short  s8v  __attribute__((ext_vector_type(8)));
typedef float  f16v __attribute__((ext_vector_type(16)));
typedef unsigned u4v __attribute__((ext_vector_type(4)));

__device__ inline unsigned pkbf(float lo, float hi) {
  unsigned r;
  asm("v_cvt_pk_bf16_f32 %0, %1, %2" : "=v"(r) : "v"(lo), "v"(hi));
  return r;
}
__device__ inline short bf16r(float f) {
  unsigned u = __float_as_uint(f);
  u += 0x7fff + ((u >> 16) & 1);
  return (short)(u >> 16);
}
__device__ inline float bfu(short s) {
  return __uint_as_float(((unsigned)(unsigned short)s) << 16);
}

// ---- K1: W^T->frag-major x8 copies (64 blk) | pos+pv zero (32 blk) |
//          x->frag-major bf16, XCD-remapped (512 blk) ------------------------
__global__ __launch_bounds__(256) void k_prep(
    const float* __restrict__ Wq, const float* __restrict__ Wk,
    const float* __restrict__ Wv, const float* __restrict__ Wo,
    const float* __restrict__ pos, const float* __restrict__ Wp1,
    const float* __restrict__ bp1, const float* __restrict__ Wp2,
    const float* __restrict__ bp2, const float* __restrict__ Wh,
    const float* __restrict__ x,
    short* __restrict__ Wtf, short* __restrict__ Wof, float* __restrict__ Ww,
    short* __restrict__ xf, float* __restrict__ pv)
{
  int bid = blockIdx.x;
  int tid = threadIdx.x;

  if (bid >= 96) {
    // x-block remap: rows [8t,8t+8) belong to b=t>>7; qkv readers for b sit
    // on XCDs 2b and 2b+1 -> t = 128*(x>>1) + 64*(x&1) + j  (x=bid&7)
    int p = bid - 96;
    int xcd = p & 7, j = p >> 3;                  // j in [0,64)
    int t = 128 * (xcd >> 1) + 64 * (xcd & 1) + j;
    size_t idx = ((size_t)t * 256 + tid) * 8;
    int m = (int)(idx >> 8), k0 = (int)(idx & 255);
    const float4* pp = (const float4*)(x + idx);
    float4 f0 = pp[0], f1 = pp[1];
    u4v o = { pkbf(f0.x, f0.y), pkbf(f0.z, f0.w), pkbf(f1.x, f1.y), pkbf(f1.z, f1.w) };
    size_t dst = ((size_t)((m >> 5) * 16 + (k0 >> 4))) * 512 + (m & 31) * 16 + (k0 & 15);
    *(u4v*)(xf + dst) = o;
    return;
  }

  if (bid < 64) {
    // W transpose + bf16 -> frag-major, written to ALL 8 per-XCD copies
    __shared__ float tile[64][65];
    int mat = bid >> 4, t = bid & 15;
    int k0t = (t >> 2) * 64, c0t = (t & 3) * 64;
    const float* W = mat == 0 ? Wq : mat == 1 ? Wk : mat == 2 ? Wv : Wo;
    float scale = (mat == 0) ? 0.2550348662f : 1.0f;   // log2(e)/sqrt(32)
#pragma unroll
    for (int i = 0; i < 16; ++i) {
      int e = tid + i * 256;
      int kr = e >> 6, cc = e & 63;
      tile[kr][cc] = W[(size_t)(k0t + kr) * 256 + c0t + cc];
    }
    __syncthreads();
#pragma unroll
    for (int i = 0; i < 16; ++i) {
      int e = tid + i * 256;
      int cr = e >> 6, kk = e & 63;
      int c = c0t + cr, k = k0t + kk;
      size_t a = ((size_t)((c >> 5) * 16 + (k >> 4))) * 512 + (c & 31) * 16 + (k & 15);
      short v = bf16r(tile[kk][cr] * scale);
      if (mat == 3) {
#pragma unroll
        for (int cp = 0; cp < 8; ++cp) Wof[(size_t)cp * WOF_CP + a] = v;
      } else {
#pragma unroll
        for (int cp = 0; cp < 8; ++cp)
          Wtf[(size_t)cp * WTF_CP + mat * 65536 + a] = v;
      }
    }
    return;
  }

  // pos branch (frozen)
  __shared__ float sWp1[256], sbp1[16], sWp2[512], sbp2[32], sWhc[32];
  __shared__ float redm[4], reds[4];
  int bh = bid - 64;
  int b = bh >> 3, h = bh & 7;
  if (tid < 32) pv[bh * 32 + tid] = 0.0f;
  sWp1[tid] = Wp1[tid];
  sWp2[tid] = Wp2[tid];
  sWp2[tid + 256] = Wp2[tid + 256];
  if (tid < 16) sbp1[tid] = bp1[tid];
  if (tid < 32) { sbp2[tid] = bp2[tid]; sWhc[tid] = Wh[tid * 8 + h]; }
  __syncthreads();

  float a[4];
#pragma unroll
  for (int nn = 0; nn < 4; ++nn) {
    int n = nn * 256 + tid;
    const float* prow = pos + (size_t)((b << 10) + n) * PD_;
    float pr[16];
#pragma unroll
    for (int r = 0; r < 16; ++r) pr[r] = prow[r];
    float h1[16];
#pragma unroll
    for (int c = 0; c < 16; ++c) {
      float v = sbp1[c];
#pragma unroll
      for (int r = 0; r < 16; ++r) v = fmaf(pr[r], sWp1[r * 16 + c], v);
      h1[c] = fmaxf(v, 0.0f);
    }
    float s = 0.0f;
#pragma unroll
    for (int d = 0; d < 32; ++d) {
      float v = sbp2[d];
#pragma unroll
      for (int c = 0; c < 16; ++c) v = fmaf(h1[c], sWp2[c * 32 + d], v);
      s = fmaf(v, sWhc[d], s);
    }
    a[nn] = -s;   // bh[h] constant over n: cancels
  }
  float m = fmaxf(fmaxf(a[0], a[1]), fmaxf(a[2], a[3]));
#pragma unroll
  for (int off = 32; off >= 1; off >>= 1) m = fmaxf(m, __shfl_xor(m, off));
  if ((tid & 63) == 0) redm[tid >> 6] = m;
  __syncthreads();
  float M = fmaxf(fmaxf(redm[0], redm[1]), fmaxf(redm[2], redm[3]));
  float e0 = __expf(a[0] - M), e1 = __expf(a[1] - M);
  float e2 = __expf(a[2] - M), e3 = __expf(a[3] - M);
  float su = e0 + e1 + e2 + e3;
#pragma unroll
  for (int off = 32; off >= 1; off >>= 1) su += __shfl_xor(su, off);
  if ((tid & 63) == 0) reds[tid >> 6] = su;
  __syncthreads();
  float inv = 1.0f / (reds[0] + reds[1] + reds[2] + reds[3]);
  float* wr = Ww + (size_t)bh * N_;
  wr[tid]        = e0 * inv;
  wr[tid + 256]  = e1 * inv;
  wr[tid + 512]  = e2 * inv;
  wr[tid + 768]  = e3 * inv;
}

// ---- K2: QKV GEMM, XCD-aligned decode + per-XCD Wtf copy  (body frozen) ----
__global__ __launch_bounds__(256) void k_qkv(
    const short* __restrict__ xf, const short* __restrict__ Wtf,
    const float* __restrict__ Ww,
    short* __restrict__ Qf, short* __restrict__ Kf, short* __restrict__ Vf,
    float* __restrict__ pv)
{
  int tid = threadIdx.x;
  int w = tid >> 6, l = tid & 63, H = l >> 5, li = l & 31;
  int bid = blockIdx.x;
  // XCD-aligned decode: block on XCD x=bid&7 handles (cb,mb) whose output
  // bh=8b+h has 2b+(h>>2)==x. b'=x>>1, hb=x&1; j=bid>>3 in [0,96).
  int xcd = bid & 7, j = bid >> 3;
  int bq = xcd >> 1, hb = xcd & 1;
  int cbi = j / 16, mbi = j % 16;
  int cb = (cbi >> 1) * 4 + 2 * hb + (cbi & 1);
  int mb = bq * 16 + mbi;
  int m0 = mb * 64 + (w & 1) * 32;
  int c0 = cb * 64 + (w >> 1) * 32;
  int mat = c0 >> 8, mc = c0 & 255;
  const short* Apf = xf + ((size_t)((m0 >> 5) * 16)) * 512 + li * 16 + 8 * H;
  const short* Bpf = Wtf + (size_t)xcd * WTF_CP + (size_t)mat * 65536
                   + ((size_t)((mc >> 5) * 16)) * 512 + li * 16 + 8 * H;
  f16v acc = {};
#pragma unroll
  for (int kc = 0; kc < 16; ++kc) {
    s8v af = *(const s8v*)(Apf + kc * 512);
    s8v bf = *(const s8v*)(Bpf + kc * 512);
    acc = __builtin_amdgcn_mfma_f32_32x32x16_bf16(af, bf, acc, 0, 0, 0);
  }
  int h = mc >> 5;
  int b = m0 >> 10, nb = m0 & 1023;
  int bh = b * 8 + h;
  if (mat < 2) {
    short* Dst = (mat == 0) ? Qf : Kf;
    size_t base = ((size_t)(bh * 2 + (li >> 4))) * 1024;
#pragma unroll
    for (int r = 0; r < 16; ++r) {
      int crow = (r & 3) + 8 * (r >> 2) + 4 * H;
      Dst[(base + nb + crow) * 16 + (li & 15)] = bf16r(acc[r]);
    }
  } else {
    int ks = nb >> 5;
#pragma unroll
    for (int q2 = 0; q2 < 4; ++q2) {
      uint2 val = make_uint2(pkbf(acc[q2 * 4 + 0], acc[q2 * 4 + 1]),
                             pkbf(acc[q2 * 4 + 2], acc[q2 * 4 + 3]));
      size_t addr = (((size_t)(bh * 32 + ks) * 2 + (q2 >> 1)) * 32 + li) * 16
                  + (q2 & 1) * 8 + 4 * H;
      *(uint2*)(Vf + addr) = val;
    }
    const float* wp = Ww + (size_t)bh * N_ + nb;
    float part = 0.0f;
#pragma unroll
    for (int r = 0; r < 16; ++r) {
      int crow = (r & 3) + 8 * (r >> 2) + 4 * H;
      part = fmaf(wp[crow], acc[r], part);
    }
    atomicAdd(&pv[bh * 32 + li], part);
  }
}

// ---- K3: flash attn, 8 waves x 128 keys  [r14-frozen, already XCD-aligned] -
__global__ __launch_bounds__(512) void k_attn(
    const short* __restrict__ Qf, const short* __restrict__ Kf,
    const short* __restrict__ Vf, const float* __restrict__ pv,
    const float* __restrict__ gate,
    short* __restrict__ OHfh, short* __restrict__ OHfl)
{
  __shared__ float sml[8][32];
  __shared__ float sO[8][32][33];
  int tid = threadIdx.x;
  int w = tid >> 6, l = tid & 63, H = l >> 5, li = l & 31;   // w in 0..7
  int bid = blockIdx.x;
  int bh = (bid & 7) * 4 + (bid >> 8);   // reader XCD == bh>>2 == producer XCD
  int qb = (bid >> 3) & 31;
  int n0 = qb * 32;

  const short* Qpf = Qf + ((size_t)(bh * 2) * 1024 + n0 + li) * 16 + 8 * H;
  s8v qf0 = *(const s8v*)(Qpf);
  s8v qf1 = *(const s8v*)(Qpf + 16384);
  const short* Kbf = Kf + ((size_t)(bh * 2) * 1024 + li) * 16 + 8 * H;
  const short* Vbf = Vf + ((size_t)(bh * 32) * 2 * 32) * 16 + li * 16 + H * 8;

  f16v acc = {};
  float lsum = 0.0f;

#pragma unroll 2
  for (int ch = 0; ch < 4; ++ch) {
    int jb = w * 128 + ch * 32;
    int ks = jb >> 5;
    const short* Kp = Kbf + (size_t)jb * 16;
    s8v kf0 = *(const s8v*)(Kp);
    s8v kf1 = *(const s8v*)(Kp + 16384);
    const short* Vp = Vbf + (size_t)(ks * 2) * 512;
    s8v vf0 = *(const s8v*)(Vp);
    s8v vf1 = *(const s8v*)(Vp + 512);

    f16v S = {};
    S = __builtin_amdgcn_mfma_f32_32x32x16_bf16(kf0, qf0, S, 0, 0, 0);
    S = __builtin_amdgcn_mfma_f32_32x32x16_bf16(kf1, qf1, S, 0, 0, 0);

    float p[16];
#pragma unroll
    for (int r = 0; r < 16; ++r) {
      p[r] = __builtin_amdgcn_exp2f(S[r]);   // no max: sigma(S)~1.44, safe
      lsum += p[r];
    }

    unsigned a0 = pkbf(p[0], p[1]),  a1 = pkbf(p[2], p[3]);
    unsigned b0 = pkbf(p[4], p[5]),  b1 = pkbf(p[6], p[7]);
    unsigned c0 = pkbf(p[8], p[9]),  c1 = pkbf(p[10], p[11]);
    unsigned d0 = pkbf(p[12], p[13]), d1 = pkbf(p[14], p[15]);
    unsigned sa0 = __shfl_xor(a0, 32), sa1 = __shfl_xor(a1, 32);
    unsigned sb0 = __shfl_xor(b0, 32), sb1 = __shfl_xor(b1, 32);
    unsigned sc0 = __shfl_xor(c0, 32), sc1 = __shfl_xor(c1, 32);
    unsigned sd0 = __shfl_xor(d0, 32), sd1 = __shfl_xor(d1, 32);
    u4v t0 = { H ? sb0 : a0, H ? sb1 : a1, H ? b0 : sa0, H ? b1 : sa1 };
    u4v t1 = { H ? sd0 : c0, H ? sd1 : c1, H ? d0 : sc0, H ? d1 : sc1 };

    acc = __builtin_amdgcn_mfma_f32_32x32x16_bf16(vf0, __builtin_bit_cast(s8v, t0), acc, 0, 0, 0);
    acc = __builtin_amdgcn_mfma_f32_32x32x16_bf16(vf1, __builtin_bit_cast(s8v, t1), acc, 0, 0, 0);
  }

  lsum += __shfl_xor(lsum, 32);
  if (H == 0) sml[w][li] = lsum;
#pragma unroll
  for (int r = 0; r < 16; ++r) {
    int d = (r & 3) + 8 * (r >> 2) + 4 * H;
    sO[w][d][li] = acc[r];
  }
  __syncthreads();

  if (tid < 256) {
    int i = tid >> 3, dq = (tid & 7) * 4;
    float L = sml[0][i] + sml[1][i] + sml[2][i] + sml[3][i]
            + sml[4][i] + sml[5][i] + sml[6][i] + sml[7][i];
    int b = bh >> 3, h = bh & 7;
    float gh = 1.0f / (1.0f + __expf(-gate[h]));
    float invL = (1.0f - gh) / L;
    const float4 pvv = *(const float4*)(pv + bh * 32 + dq);
    float o[4];
#pragma unroll
    for (int q = 0; q < 4; ++q) {
      o[q] = (sO[0][dq + q][i] + sO[1][dq + q][i] + sO[2][dq + q][i] + sO[3][dq + q][i]
            + sO[4][dq + q][i] + sO[5][dq + q][i] + sO[6][dq + q][i] + sO[7][dq + q][i]) * invL;
    }
    o[0] += gh * pvv.x; o[1] += gh * pvv.y; o[2] += gh * pvv.z; o[3] += gh * pvv.w;
    float hi[4], lo[4];
#pragma unroll
    for (int q = 0; q < 4; ++q) {
      hi[q] = bfu(bf16r(o[q]));
      lo[q] = o[q] - hi[q];
    }
    int kc = h * 2 + (dq >> 4);
    int rem = dq & 15;                     // {0,4,8,12}
    size_t addr = ((size_t)((b * 32 + qb) * 16 + kc)) * 512 + i * 16 + rem;
    *(uint2*)(OHfh + addr) = make_uint2(pkbf(hi[0], hi[1]), pkbf(hi[2], hi[3]));
    *(uint2*)(OHfl + addr) = make_uint2(pkbf(lo[0], lo[1]), pkbf(lo[2], lo[3]));
  }
}

// ---- K4: out GEMM, XCD-aligned decode + per-XCD Wof copy  (body frozen) ----
__global__ __launch_bounds__(256) void k_out(
    const short* __restrict__ OHfh, const short* __restrict__ OHfl,
    const short* __restrict__ Wof, const float* __restrict__ bo,
    float* __restrict__ out)
{
  int tid = threadIdx.x;
  int w = tid >> 6, l = tid & 63, H = l >> 5, li = l & 31;
  int bid = blockIdx.x;
  // XCD-aligned decode: rows of batch b were produced on XCDs 2b/2b+1.
  int xcd = bid & 7, j = bid >> 3;           // j in [0,32)
  int bq = xcd >> 1, e = xcd & 1;
  int o_ = bq * 64 + e * 32 + j;             // original block index
  int m0 = (o_ >> 2) * 64 + (w & 1) * 32;
  int c0 = (o_ & 3) * 64 + (w >> 1) * 32;
  const short* Ahf = OHfh + ((size_t)((m0 >> 5) * 16)) * 512 + li * 16 + 8 * H;
  const short* Alf = OHfl + ((size_t)((m0 >> 5) * 16)) * 512 + li * 16 + 8 * H;
  const short* Bpf = Wof + (size_t)xcd * WOF_CP
                   + ((size_t)((c0 >> 5) * 16)) * 512 + li * 16 + 8 * H;
  f16v acc = {};
#pragma unroll
  for (int kc = 0; kc < 16; ++kc) {
    s8v bf = *(const s8v*)(Bpf + kc * 512);
    s8v ah = *(const s8v*)(Ahf + kc * 512);
    s8v al = *(const s8v*)(Alf + kc * 512);
    acc = __builtin_amdgcn_mfma_f32_32x32x16_bf16(ah, bf, acc, 0, 0, 0);
    acc = __builtin_amdgcn_mfma_f32_32x32x16_bf16(al, bf, acc, 0, 0, 0);
  }
  float bias = bo[c0 + li];
#pragma unroll
  for (int r = 0; r < 16; ++r) {
    int crow = (r & 3) + 8 * (r >> 2) + 4 * H;
    out[(size_t)(m0 + crow) * 256 + c0 + li] = acc[r] + bias;
  }
}

// ============================================================================
extern "C" void kernel_launch(void* const* d_in, const int* in_sizes, int n_in,
                              void* d_out, int out_size, void* d_ws, size_t ws_size,
                              hipStream_t stream) {
  const float* x    = (const float*)d_in[0];
  // d_in[1] = deep_semantics: unused by the reference
  const float* pos  = (const float*)d_in[2];
  const float* Wq   = (const float*)d_in[3];
  const float* Wk   = (const float*)d_in[4];
  const float* Wv   = (const float*)d_in[5];
  const float* Wo   = (const float*)d_in[6];
  const float* bo   = (const float*)d_in[7];
  const float* Wp1  = (const float*)d_in[8];
  const float* bp1  = (const float*)d_in[9];
  const float* Wp2  = (const float*)d_in[10];
  const float* bp2  = (const float*)d_in[11];
  const float* Wh   = (const float*)d_in[12];
  // d_in[13] = bh: cancels in softmax over keys
  const float* gate = (const float*)d_in[14];
  float* out = (float*)d_out;

  char* base = (char*)d_ws;
  short* Qf   = (short*)(base);                               // 2MB
  short* Kf   = (short*)(base + (2u << 20));                  // 2MB
  short* Vf   = (short*)(base + (4u << 20));                  // 2MB
  short* OHfh = (short*)(base + (6u << 20));                  // 2MB
  short* OHfl = (short*)(base + (8u << 20));                  // 2MB
  short* xf   = (short*)(base + (10u << 20));                 // 2MB
  short* Wtf  = (short*)(base + (12u << 20));                 // 3MB (8 copies)
  short* Wof  = (short*)(base + (15u << 20));                 // 1MB (8 copies)
  float* Ww   = (float*)(base + (16u << 20));                 // 128KB
  float* pv   = (float*)(base + (16u << 20) + (128u << 10));  // 4KB

  k_prep<<<608,  256, 0, stream>>>(Wq, Wk, Wv, Wo, pos, Wp1, bp1, Wp2, bp2, Wh,
                                   x, Wtf, Wof, Ww, xf, pv);
  k_qkv <<<768,  256, 0, stream>>>(xf, Wtf, Ww, Qf, Kf, Vf, pv);
  k_attn<<<1024, 512, 0, stream>>>(Qf, Kf, Vf, pv, gate, OHfh, OHfl);
  k_out <<<256,  256, 0, stream>>>(OHfh, OHfl, Wof, bo, out);
}